// Round 1
// baseline (631.485 us; speedup 1.0000x reference)
//
#include <hip/hip_runtime.h>

#define NU_ 100000
#define NI_ 50000
#define D_  128
#define C_  5
#define V_  200000
#define E_  200000
#define L_  10

typedef __bf16 bf16x8 __attribute__((ext_vector_type(8)));
typedef unsigned short u16;
typedef u16 u16x8 __attribute__((ext_vector_type(8)));
typedef float f32x4 __attribute__((ext_vector_type(4)));

// ws layout (bytes): [0..4) loss accumulator f32; [256..) bf16 weight buffer:
//   w1r' [0,32768) elems (K=256), w2r' [32768,49152) (K=128),
//   w1t' [49152,81920), w2t' [81920,98304)
#define W1R_OFF 0
#define W2R_OFF 32768
#define W1T_OFF 49152
#define W2T_OFF 81920
#define WTOT    98304

__device__ __forceinline__ u16 f2bf(float x) {
    union { float f; unsigned int u; } v; v.f = x;
    unsigned int u = v.u;
    return (u16)((u + 0x7FFFu + ((u >> 16) & 1u)) >> 16);
}

// Convert weights f32 -> bf16 in MFMA B-fragment-friendly swizzle:
// dest[((k>>3)*128 + n)*8 + (k&7)] = W[k*128 + n]
__global__ void prep_kernel(const float* __restrict__ w1r, const float* __restrict__ w2r,
                            const float* __restrict__ w1t, const float* __restrict__ w2t,
                            u16* __restrict__ wbuf, float* __restrict__ loss_acc) {
    int idx = blockIdx.x * blockDim.x + threadIdx.x;
    if (idx == 0) *loss_acc = 0.f;
    if (idx >= WTOT) return;
    const float* src; int base;
    if (idx < W2R_OFF)      { src = w1r; base = W1R_OFF; }
    else if (idx < W1T_OFF) { src = w2r; base = W2R_OFF; }
    else if (idx < W2T_OFF) { src = w1t; base = W1T_OFF; }
    else                    { src = w2t; base = W2T_OFF; }
    int local = idx - base;
    int j = local & 7;
    int g = local >> 3;
    int n = g & 127;
    int kq = g >> 7;
    int k = kq * 8 + j;
    wbuf[idx] = f2bf(src[k * 128 + n]);
}

// Stage 16 edges of concat([ut[src], it[dst]]) (256 dims) as bf16 into LDS
// in A-fragment layout: buf[(k8*16 + m)*8 + j], k = k8*8+j.
__device__ __forceinline__ void stage_pair(const float* __restrict__ ut,
                                           const float* __restrict__ it,
                                           const int* __restrict__ srcI,
                                           const int* __restrict__ dstI,
                                           int ebase, int lane, u16* buf) {
    int m = lane >> 2;       // edge row 0..15
    int part = lane & 3;     // 0,1 -> user feat; 2,3 -> item feat
    int e = ebase + m;
    const float* row = (part < 2) ? (ut + (size_t)srcI[e] * D_)
                                  : (it + (size_t)dstI[e] * D_);
    const float* seg = row + (part & 1) * 64;
    int k8base = part * 8;
#pragma unroll
    for (int i = 0; i < 8; i++) {
        float4 a = *(const float4*)(seg + i * 8);
        float4 b = *(const float4*)(seg + i * 8 + 4);
        u16x8 v;
        v[0] = f2bf(a.x); v[1] = f2bf(a.y); v[2] = f2bf(a.z); v[3] = f2bf(a.w);
        v[4] = f2bf(b.x); v[5] = f2bf(b.y); v[6] = f2bf(b.z); v[7] = f2bf(b.w);
        *(u16x8*)(buf + ((k8base + i) * 16 + m) * 8) = v;
    }
}

// 16 (edges) x 128 (cols) tile GEMM, K = KT*32. A frags from LDS, B frags from
// pre-swizzled global bf16 weights. acc[nt] accumulates n-tile nt (16 cols).
template <int KT>
__device__ __forceinline__ void gemm_tile(const u16* aLDS, const u16* __restrict__ Wg,
                                          int lq, int ln, f32x4 acc[8]) {
#pragma unroll
    for (int kt = 0; kt < KT; kt++) {
        bf16x8 af = *(const bf16x8*)(aLDS + ((kt * 4 + lq) * 16 + ln) * 8);
#pragma unroll
        for (int nt = 0; nt < 8; nt++) {
            bf16x8 bfv = *(const bf16x8*)(Wg + (size_t)((kt * 4 + lq) * 128 + nt * 16 + ln) * 8);
            acc[nt] = __builtin_amdgcn_mfma_f32_16x16x32_bf16(af, bfv, acc[nt], 0, 0, 0);
        }
    }
}

// relu(acc) -> LDS bf16 in A-fragment layout (for next GEMM's A operand).
__device__ __forceinline__ void store_h_relu(const f32x4 acc[8], u16* buf, int lq, int ln) {
#pragma unroll
    for (int nt = 0; nt < 8; nt++) {
#pragma unroll
        for (int reg = 0; reg < 4; reg++) {
            float h = fmaxf(acc[nt][reg], 0.f);
            int dcol = nt * 16 + ln;               // column 0..127 (= k of next GEMM)
            int r = lq * 4 + reg;                  // row 0..15
            buf[((dcol >> 3) * 16 + r) * 8 + (dcol & 7)] = f2bf(h);
        }
    }
}

__global__ __launch_bounds__(256, 3) void fused_kernel(
    const float* __restrict__ urf, const float* __restrict__ irf,
    const float* __restrict__ utf, const float* __restrict__ itf,
    const float* __restrict__ wp, const float* __restrict__ emb,
    const int* __restrict__ srcI, const int* __restrict__ dstI,
    const int* __restrict__ sidI, const int* __restrict__ nsidI,
    const u16* __restrict__ wbuf, float* __restrict__ loss_acc,
    float* __restrict__ out) {
    __shared__ u16 smem[4 * 6144];   // per wave: 4096 (bufA) + 2048 (bufB) u16
    const int tid = threadIdx.x;
    const int w = tid >> 6;
    const int lane = tid & 63;
    const int lq = lane >> 4;    // quad 0..3
    const int ln = lane & 15;    // row/col within tile
    u16* bufA = smem + w * 6144;
    u16* bufB = bufA + 4096;
    const int ebase = blockIdx.x * 64 + w * 16;

    // ---------- rating path ----------
    stage_pair(urf, irf, srcI, dstI, ebase, lane, bufA);
    __syncthreads();

    f32x4 rh[8];
    {
        f32x4 acc[8];
#pragma unroll
        for (int nt = 0; nt < 8; nt++) acc[nt] = (f32x4){0.f, 0.f, 0.f, 0.f};
        gemm_tile<8>(bufA, wbuf + W1R_OFF, lq, ln, acc);   // relu(rf@w1r)
        store_h_relu(acc, bufB, lq, ln);
    }
    __syncthreads();
    {
#pragma unroll
        for (int nt = 0; nt < 8; nt++) rh[nt] = (f32x4){0.f, 0.f, 0.f, 0.f};
        gemm_tile<4>(bufB, wbuf + W2R_OFF, lq, ln, rh);    // rh = h1 @ w2r
    }

    // ---------- pr = rh @ wp ----------
    {
        float pp[4][5];
#pragma unroll
        for (int r = 0; r < 4; r++)
#pragma unroll
            for (int c = 0; c < 5; c++) pp[r][c] = 0.f;
#pragma unroll
        for (int nt = 0; nt < 8; nt++) {
            int d = nt * 16 + ln;
            float wpc[5];
#pragma unroll
            for (int c = 0; c < 5; c++) wpc[c] = wp[d * 5 + c];
#pragma unroll
            for (int reg = 0; reg < 4; reg++)
#pragma unroll
                for (int c = 0; c < 5; c++) pp[reg][c] += rh[nt][reg] * wpc[c];
        }
#pragma unroll
        for (int off = 1; off < 16; off <<= 1)
#pragma unroll
            for (int reg = 0; reg < 4; reg++)
#pragma unroll
                for (int c = 0; c < 5; c++)
                    pp[reg][c] += __shfl_xor(pp[reg][c], off, 64);
        if (ln == 0) {
#pragma unroll
            for (int reg = 0; reg < 4; reg++) {
                int e = ebase + lq * 4 + reg;
#pragma unroll
                for (int c = 0; c < 5; c++) out[(size_t)e * 5 + c] = pp[reg][c];
            }
        }
    }

    // ---------- topic path (residual: C-init = rh) ----------
    __syncthreads();
    stage_pair(utf, itf, srcI, dstI, ebase, lane, bufA);
    __syncthreads();
    f32x4 acc[8];
    {
#pragma unroll
        for (int nt = 0; nt < 8; nt++) acc[nt] = (f32x4){0.f, 0.f, 0.f, 0.f};
        gemm_tile<8>(bufA, wbuf + W1T_OFF, lq, ln, acc);   // relu(tf@w1t)
        store_h_relu(acc, bufB, lq, ln);
    }
    __syncthreads();
#pragma unroll
    for (int nt = 0; nt < 8; nt++) acc[nt] = rh[nt];       // residual
    gemm_tile<4>(bufB, wbuf + W2T_OFF, lq, ln, acc);       // th = h1t@w2t + rh

    // th -> LDS f32 (overlay bufA: 16*128*4B = 8KB exact)
    float* thb = (float*)bufA;
#pragma unroll
    for (int nt = 0; nt < 8; nt++)
#pragma unroll
        for (int reg = 0; reg < 4; reg++)
            thb[(lq * 4 + reg) * 128 + nt * 16 + ln] = acc[nt][reg];
    __syncthreads();

    // ---------- review gather + scores + loss ----------
    float wave_loss = 0.f;
    for (int m = 0; m < 16; m++) {
        int e = ebase + m;
        float2 t = *(const float2*)(thb + m * 128 + lane * 2);
        float p0 = 0.f, p1 = 0.f, q0 = 0.f, q1 = 0.f;
        int pcnt = 0, ncnt = 0;
#pragma unroll
        for (int i = 0; i < L_; i++) {
            int s = sidI[e * L_ + i];             // wave-uniform -> s_load
            pcnt += (s > 0) ? 1 : 0;
            float2 ev = *(const float2*)(emb + (size_t)s * D_ + lane * 2);
            p0 += ev.x; p1 += ev.y;
        }
#pragma unroll
        for (int i = 0; i < L_; i++) {
            int s = nsidI[e * L_ + i];
            ncnt += (s > 0) ? 1 : 0;
            float2 ev = *(const float2*)(emb + (size_t)s * D_ + lane * 2);
            q0 += ev.x; q1 += ev.y;
        }
        float ps = t.x * p0 + t.y * p1;
        float ns = t.x * q0 + t.y * q1;
#pragma unroll
        for (int off = 1; off < 64; off <<= 1) {
            ps += __shfl_xor(ps, off, 64);
            ns += __shfl_xor(ns, off, 64);
        }
        ps /= ((float)pcnt + 1e-9f);
        ns /= ((float)ncnt + 1e-9f);
        float x = ns - ps;                         // -(pos - neg)
        wave_loss += fmaxf(x, 0.f) + log1pf(expf(-fabsf(x)));  // softplus(x)
    }
    if (lane == 0) atomicAdd(loss_acc, wave_loss);
}

__global__ void finish_kernel(const float* __restrict__ loss_acc, float* __restrict__ out) {
    float v = loss_acc[0] * (1.0f / (float)E_);
    out[(size_t)E_ * C_]     = v;
    out[(size_t)E_ * C_ + 1] = v;
}

extern "C" void kernel_launch(void* const* d_in, const int* in_sizes, int n_in,
                              void* d_out, int out_size, void* d_ws, size_t ws_size,
                              hipStream_t stream) {
    const float* urf = (const float*)d_in[0];
    const float* irf = (const float*)d_in[1];
    const float* utf = (const float*)d_in[2];
    const float* itf = (const float*)d_in[3];
    const float* w1r = (const float*)d_in[4];
    const float* w2r = (const float*)d_in[5];
    const float* w1t = (const float*)d_in[6];
    const float* w2t = (const float*)d_in[7];
    const float* wp  = (const float*)d_in[8];
    const float* emb = (const float*)d_in[9];
    const int* srcI  = (const int*)d_in[10];
    const int* dstI  = (const int*)d_in[11];
    const int* sidI  = (const int*)d_in[12];
    const int* nsidI = (const int*)d_in[13];
    float* out = (float*)d_out;

    float* loss_acc = (float*)d_ws;
    u16* wbuf = (u16*)((char*)d_ws + 256);

    prep_kernel<<<(WTOT + 255) / 256, 256, 0, stream>>>(w1r, w2r, w1t, w2t, wbuf, loss_acc);
    fused_kernel<<<E_ / 64, 256, 0, stream>>>(urf, irf, utf, itf, wp, emb,
                                              srcI, dstI, sidI, nsidI,
                                              wbuf, loss_acc, out);
    finish_kernel<<<1, 1, 0, stream>>>(loss_acc, out);
}